// Round 2
// baseline (955.263 us; speedup 1.0000x reference)
//
#include <hip/hip_runtime.h>

// GRU: B=4096, T=512, I=32, H=32, head -> y[B]
// Half-wave (32 lanes) per batch; lane j owns hidden unit j.
// 192 weights/lane pinned to arch VGPRs (asm "+v" defeats AGPR spill).
// x: direct global float4 broadcast loads (VMEM pipe, L1/L2-served).
// h: LDS roundtrip (write 1 b32, read 8 b128 broadcasts) - only LDS user.

#define TSTEPS 512

#define PIN4(a, i) asm volatile("" : "+v"(a[i]), "+v"(a[i+1]), "+v"(a[i+2]), "+v"(a[i+3]))

__global__ __launch_bounds__(256, 2)
void gru_fused_kernel(const float* __restrict__ x,
                      const float* __restrict__ W_ih,
                      const float* __restrict__ W_hh,
                      const float* __restrict__ b_ih,
                      const float* __restrict__ b_hh,
                      const float* __restrict__ w_head,
                      const float* __restrict__ b_head,
                      float* __restrict__ y)
{
    const int tid = threadIdx.x;
    const int hw  = tid >> 5;    // half-wave id in block: 0..7
    const int j   = tid & 31;    // hidden unit index
    const int b   = blockIdx.x * 8 + hw;

    // per-halfwave LDS: h vector only (x no longer staged in LDS)
    __shared__ float hsh[8 * 32];
    float* hs = &hsh[hw * 32];

    // ---- weights into registers (prescale-free; same math as round 1)
    float wr[32], wz[32], wn[32], ur[32], uz[32], un[32];
#pragma unroll
    for (int k = 0; k < 32; ++k) {
        wr[k] = W_ih[(j)      * 32 + k];
        wz[k] = W_ih[(32 + j) * 32 + k];
        wn[k] = W_ih[(64 + j) * 32 + k];
        ur[k] = W_hh[(j)      * 32 + k];
        uz[k] = W_hh[(32 + j) * 32 + k];
        un[k] = W_hh[(64 + j) * 32 + k];
    }
    float br  = b_ih[j]      + b_hh[j];        // combined reset bias
    float bz  = b_ih[32 + j] + b_hh[32 + j];   // combined update bias
    float bni = b_ih[64 + j];                  // new-gate input bias
    float bnh = b_hh[64 + j];                  // new-gate hidden bias

    float h = 0.0f;
    const float* xrow = x + (size_t)b * TSTEPS * 32;

    for (int t = 0; t < TSTEPS; ++t) {
        // Pin all weights into arch VGPRs every iteration: forbids AGPR
        // storage and remat-from-global. Empty asm -> zero instructions
        // when the value already lives in a VGPR.
#pragma unroll
        for (int q = 0; q < 32; q += 4) {
            PIN4(wr, q); PIN4(wz, q); PIN4(wn, q);
            PIN4(ur, q); PIN4(uz, q); PIN4(un, q);
        }
        asm volatile("" : "+v"(br), "+v"(bz), "+v"(bni), "+v"(bnh));

        hs[j] = h;   // stage h for broadcast (same-wave write->read)

        float ar = br, az = bz, an = bni, ah = bnh;

        // ---- x phase: direct global broadcast loads (covers LDS latency)
        const float4* xv4 = (const float4*)(xrow + (size_t)t * 32);
#pragma unroll
        for (int q = 0; q < 8; ++q) {
            const float4 xq = xv4[q];
            ar = fmaf(wr[4*q+0], xq.x, ar); ar = fmaf(wr[4*q+1], xq.y, ar);
            ar = fmaf(wr[4*q+2], xq.z, ar); ar = fmaf(wr[4*q+3], xq.w, ar);
            az = fmaf(wz[4*q+0], xq.x, az); az = fmaf(wz[4*q+1], xq.y, az);
            az = fmaf(wz[4*q+2], xq.z, az); az = fmaf(wz[4*q+3], xq.w, az);
            an = fmaf(wn[4*q+0], xq.x, an); an = fmaf(wn[4*q+1], xq.y, an);
            an = fmaf(wn[4*q+2], xq.z, an); an = fmaf(wn[4*q+3], xq.w, an);
        }

        // ---- h phase: LDS float4 broadcast reads
        const float4* h4 = (const float4*)hs;
#pragma unroll
        for (int q = 0; q < 8; ++q) {
            const float4 hq = h4[q];
            ar = fmaf(ur[4*q+0], hq.x, ar); ar = fmaf(ur[4*q+1], hq.y, ar);
            ar = fmaf(ur[4*q+2], hq.z, ar); ar = fmaf(ur[4*q+3], hq.w, ar);
            az = fmaf(uz[4*q+0], hq.x, az); az = fmaf(uz[4*q+1], hq.y, az);
            az = fmaf(uz[4*q+2], hq.z, az); az = fmaf(uz[4*q+3], hq.w, az);
            ah = fmaf(un[4*q+0], hq.x, ah); ah = fmaf(un[4*q+1], hq.y, ah);
            ah = fmaf(un[4*q+2], hq.z, ah); ah = fmaf(un[4*q+3], hq.w, ah);
        }

        // ---- gates (identical numerics to round 1, which passed)
        const float r  = 1.0f / (1.0f + __expf(-ar));
        const float z  = 1.0f / (1.0f + __expf(-az));
        const float nv = an + r * ah;
        const float e  = __expf(2.0f * nv);
        const float n  = 1.0f - 2.0f / (e + 1.0f);   // tanh(nv)
        h = n + z * (h - n);
    }

    // ---- head: y[b] = sum_j h_j * w_head[j] + b_head
    float acc = h * w_head[j];
#pragma unroll
    for (int m = 16; m >= 1; m >>= 1)
        acc += __shfl_xor(acc, m, 32);
    if (j == 0)
        y[b] = acc + b_head[0];
}

extern "C" void kernel_launch(void* const* d_in, const int* in_sizes, int n_in,
                              void* d_out, int out_size, void* d_ws, size_t ws_size,
                              hipStream_t stream) {
    const float* x      = (const float*)d_in[0];
    const float* W_ih   = (const float*)d_in[1];
    const float* W_hh   = (const float*)d_in[2];
    const float* b_ih   = (const float*)d_in[3];
    const float* b_hh   = (const float*)d_in[4];
    const float* w_head = (const float*)d_in[5];
    const float* b_head = (const float*)d_in[6];
    float* y = (float*)d_out;

    const int B = 4096;
    dim3 grid(B / 8), block(256);
    gru_fused_kernel<<<grid, block, 0, stream>>>(x, W_ih, W_hh, b_ih, b_hh,
                                                 w_head, b_head, y);
}

// Round 3
// 948.284 us; speedup vs baseline: 1.0074x; 1.0074x over previous
//
#include <hip/hip_runtime.h>

// GRU: B=4096, T=512, I=32, H=32, head -> y[B]
// One wave64 per batch. Lane (j = l&31, p = l>>5) owns hidden unit j,
// k-half p: weight rows {j, 32+j, 64+j} of W_ih/W_hh restricted to
// k in [16p, 16p+16) -> 96 weights/lane (fits 128 VGPRs, 4 waves/SIMD).
// Per step: one wave-wide ds_write stages {x_t (lanes 0..31), h (lanes
// 32..63)}; broadcast ds_read_b128 quads feed 96 FMAs; k-halves combined
// with __shfl_xor(.,32); gates computed redundantly on all lanes.

#define TSTEPS 512

__global__ __launch_bounds__(256, 4)
void gru_fused_kernel(const float* __restrict__ x,
                      const float* __restrict__ W_ih,
                      const float* __restrict__ W_hh,
                      const float* __restrict__ b_ih,
                      const float* __restrict__ b_hh,
                      const float* __restrict__ w_head,
                      const float* __restrict__ b_head,
                      float* __restrict__ y)
{
    const int tid  = threadIdx.x;
    const int wave = tid >> 6;          // 0..3
    const int l    = tid & 63;
    const int j    = l & 31;            // hidden unit
    const int p    = l >> 5;            // k-half: 0 or 1
    const int b    = blockIdx.x * 4 + wave;
    const int k0   = p * 16;

    // per-wave LDS: [0..31] = x_t row, [32..63] = h vector
    __shared__ float sh[4][64];
    float* s = sh[wave];

    // ---- 96 weights per lane
    float wr[16], wz[16], wn[16], ur[16], uz[16], un[16];
#pragma unroll
    for (int kk = 0; kk < 16; ++kk) {
        wr[kk] = W_ih[(j)      * 32 + k0 + kk];
        wz[kk] = W_ih[(32 + j) * 32 + k0 + kk];
        wn[kk] = W_ih[(64 + j) * 32 + k0 + kk];
        ur[kk] = W_hh[(j)      * 32 + k0 + kk];
        uz[kk] = W_hh[(32 + j) * 32 + k0 + kk];
        un[kk] = W_hh[(64 + j) * 32 + k0 + kk];
    }
    // biases only on the p==0 half so the shfl-combine adds them exactly once
    const float br  = p ? 0.0f : (b_ih[j]      + b_hh[j]);
    const float bz  = p ? 0.0f : (b_ih[32 + j] + b_hh[32 + j]);
    const float bni = p ? 0.0f : b_ih[64 + j];
    const float bnh = p ? 0.0f : b_hh[64 + j];

    const float* xrow = x + (size_t)b * TSTEPS * 32;

    float h  = 0.0f;
    float xv = xrow[j];                 // prefetch x[0][j]

    #pragma unroll 1
    for (int t = 0; t < TSTEPS; ++t) {
        // stage: lanes 0..31 write x_t, lanes 32..63 write h (one ds_write_b32)
        s[l] = (l < 32) ? xv : h;

        // prefetch x for next step (full step of latency cover)
        const int tn = (t + 1 < TSTEPS) ? (t + 1) : t;
        xv = xrow[(size_t)tn * 32 + j];

        float ar = br, az = bz, an = bni, ah = bnh;
        const float4* S4 = (const float4*)s;   // quads 0..7 = x, 8..15 = h
#pragma unroll
        for (int q = 0; q < 4; ++q) {
            const float4 xq = S4[4 * p + q];       // broadcast read
            ar = fmaf(wr[4*q+0], xq.x, ar); ar = fmaf(wr[4*q+1], xq.y, ar);
            ar = fmaf(wr[4*q+2], xq.z, ar); ar = fmaf(wr[4*q+3], xq.w, ar);
            az = fmaf(wz[4*q+0], xq.x, az); az = fmaf(wz[4*q+1], xq.y, az);
            az = fmaf(wz[4*q+2], xq.z, az); az = fmaf(wz[4*q+3], xq.w, az);
            an = fmaf(wn[4*q+0], xq.x, an); an = fmaf(wn[4*q+1], xq.y, an);
            an = fmaf(wn[4*q+2], xq.z, an); an = fmaf(wn[4*q+3], xq.w, an);
            const float4 hq = S4[8 + 4 * p + q];   // broadcast read
            ar = fmaf(ur[4*q+0], hq.x, ar); ar = fmaf(ur[4*q+1], hq.y, ar);
            ar = fmaf(ur[4*q+2], hq.z, ar); ar = fmaf(ur[4*q+3], hq.w, ar);
            az = fmaf(uz[4*q+0], hq.x, az); az = fmaf(uz[4*q+1], hq.y, az);
            az = fmaf(uz[4*q+2], hq.z, az); az = fmaf(uz[4*q+3], hq.w, az);
            ah = fmaf(un[4*q+0], hq.x, ah); ah = fmaf(un[4*q+1], hq.y, ah);
            ah = fmaf(un[4*q+2], hq.z, ah); ah = fmaf(un[4*q+3], hq.w, ah);
        }

        // combine k-halves (lane l <-> l^32); both halves end with full sums
        ar += __shfl_xor(ar, 32);
        az += __shfl_xor(az, 32);
        an += __shfl_xor(an, 32);
        ah += __shfl_xor(ah, 32);

        // gates (same numerics as the passing round-1 kernel)
        const float r  = 1.0f / (1.0f + __expf(-ar));
        const float z  = 1.0f / (1.0f + __expf(-az));
        const float nv = an + r * ah;
        const float e  = __expf(2.0f * nv);
        const float n  = 1.0f - 2.0f / (e + 1.0f);   // tanh(nv)
        h = n + z * (h - n);
    }

    // ---- head: y[b] = sum_j h_j * w_head[j] + b_head
    float acc = h * w_head[j];
#pragma unroll
    for (int m = 16; m >= 1; m >>= 1)
        acc += __shfl_xor(acc, m);     // reduces within each 32-lane half
    if (l == 0)
        y[b] = acc + b_head[0];
}

extern "C" void kernel_launch(void* const* d_in, const int* in_sizes, int n_in,
                              void* d_out, int out_size, void* d_ws, size_t ws_size,
                              hipStream_t stream) {
    const float* x      = (const float*)d_in[0];
    const float* W_ih   = (const float*)d_in[1];
    const float* W_hh   = (const float*)d_in[2];
    const float* b_ih   = (const float*)d_in[3];
    const float* b_hh   = (const float*)d_in[4];
    const float* w_head = (const float*)d_in[5];
    const float* b_head = (const float*)d_in[6];
    float* y = (float*)d_out;

    const int B = 4096;
    dim3 grid(B / 4), block(256);
    gru_fused_kernel<<<grid, block, 0, stream>>>(x, W_ih, W_hh, b_ih, b_hh,
                                                 w_head, b_head, y);
}